// Round 1
// baseline (463.558 us; speedup 1.0000x reference)
//
#include <hip/hip_runtime.h>

#define N_ITEMS   2000
#define N_STORAGE 4094
#define N_LOCS    4096        // N_STORAGE + 2
#define E_EDGES   4194304

// d_ws layout (int32 elements):
//   loc_win : N_LOCS*N_LOCS      winner edge-id for loc_mat[ls][ld], -1 = empty
//   seq_win : N_ITEMS*N_ITEMS    winner edge-id for seq_mat[i][j],  -1 = empty
//   item_win: N_ITEMS            winner edge-id for item_to_loc[i], -1 = empty
//   item_loc: N_ITEMS            resolved storage loc per item (0 if none)
//   comps   : 3 floats           [item_item_dist, start_dist, end_dist]

__global__ void scatter_edges(const int* __restrict__ src, const int* __restrict__ dst,
                              int* __restrict__ loc_win, int* __restrict__ seq_win,
                              int* __restrict__ item_win) {
    int stride = gridDim.x * blockDim.x;
    for (int e = blockIdx.x * blockDim.x + threadIdx.x; e < E_EDGES; e += stride) {
        int s = src[e], d = dst[e];
        if (s >= N_ITEMS) {
            // type 0: loc-loc
            int ls = s - N_ITEMS, ld = d - N_ITEMS;
            if (ls < N_LOCS && ld >= 0 && ld < N_LOCS)
                atomicMax(&loc_win[ls * N_LOCS + ld], e);
        } else if (s >= 0) {
            if (d >= 0 && d < N_ITEMS) {
                // type 1: item-item
                atomicMax(&seq_win[s * N_ITEMS + d], e);
            } else {
                // type 2: item -> storage loc
                int li = d - N_ITEMS;
                if (li >= 0 && li < N_STORAGE)
                    atomicMax(&item_win[s], e);
            }
        }
    }
}

// Resolve item_to_loc (last valid edge wins; default 0), and accumulate
// start_dist = sum_i loc_mat[N_STORAGE, loc_i], end_dist = sum_i loc_mat[loc_i, N_STORAGE+1]
__global__ void resolve_items(const int* __restrict__ dst, const float* __restrict__ attr,
                              const int* __restrict__ item_win, const int* __restrict__ loc_win,
                              int* __restrict__ item_loc, float* __restrict__ comps) {
    int i = blockIdx.x * blockDim.x + threadIdx.x;
    float sd = 0.f, ed = 0.f;
    if (i < N_ITEMS) {
        int w = item_win[i];
        int loc = (w >= 0) ? (dst[w] - N_ITEMS) : 0;
        item_loc[i] = loc;
        int lw1 = loc_win[N_STORAGE * N_LOCS + loc];          // start row
        int lw2 = loc_win[loc * N_LOCS + (N_STORAGE + 1)];    // end col
        sd = (lw1 >= 0) ? attr[lw1 * 2 + 0] : 0.f;
        ed = (lw2 >= 0) ? attr[lw2 * 2 + 0] : 0.f;
    }
    #pragma unroll
    for (int o = 32; o > 0; o >>= 1) {
        sd += __shfl_down(sd, o);
        ed += __shfl_down(ed, o);
    }
    if ((threadIdx.x & 63) == 0) {
        atomicAdd(&comps[1], sd);
        atomicAdd(&comps[2], ed);
    }
}

// item_item_dist = sum over seq slots with a winner and seq>0 of seq * loc_mat[loc_i, loc_j]
__global__ void seq_reduce(const float* __restrict__ attr, const int* __restrict__ seq_win,
                           const int* __restrict__ loc_win, const int* __restrict__ item_loc,
                           float* __restrict__ comps) {
    __shared__ int s_loc[N_ITEMS];
    for (int t = threadIdx.x; t < N_ITEMS; t += blockDim.x) s_loc[t] = item_loc[t];
    __syncthreads();

    const int total = N_ITEMS * N_ITEMS;
    int stride = gridDim.x * blockDim.x;
    float acc = 0.f;
    for (int slot = blockIdx.x * blockDim.x + threadIdx.x; slot < total; slot += stride) {
        int w = seq_win[slot];
        if (w < 0) continue;
        float seq = attr[w * 2 + 1];
        if (!(seq > 0.f)) continue;
        int i = slot / N_ITEMS;
        int j = slot - i * N_ITEMS;
        int lw = loc_win[s_loc[i] * N_LOCS + s_loc[j]];
        if (lw >= 0) acc += seq * attr[lw * 2 + 0];
    }
    #pragma unroll
    for (int o = 32; o > 0; o >>= 1) acc += __shfl_down(acc, o);
    if ((threadIdx.x & 63) == 0) atomicAdd(&comps[0], acc);
}

// pred = relu(comps @ W1 + b1) @ W2 + b2   (comps: [1,3], W1: [3,32], W2: [32,1])
__global__ void mlp_final(const float* __restrict__ comps, const float* __restrict__ W1,
                          const float* __restrict__ b1, const float* __restrict__ W2,
                          const float* __restrict__ b2, float* __restrict__ out) {
    int t = threadIdx.x;
    float v = 0.f;
    if (t < 32) {
        float h = comps[0] * W1[0 * 32 + t] + comps[1] * W1[1 * 32 + t] +
                  comps[2] * W1[2 * 32 + t] + b1[t];
        h = fmaxf(h, 0.f);
        v = h * W2[t];
    }
    #pragma unroll
    for (int o = 32; o > 0; o >>= 1) v += __shfl_down(v, o);
    if (t == 0) out[0] = v + b2[0];
}

extern "C" void kernel_launch(void* const* d_in, const int* in_sizes, int n_in,
                              void* d_out, int out_size, void* d_ws, size_t ws_size,
                              hipStream_t stream) {
    const int*   eidx = (const int*)d_in[0];     // [2, E] int32
    const int*   src  = eidx;
    const int*   dst  = eidx + E_EDGES;
    const float* attr = (const float*)d_in[1];   // [E, 2] f32
    // d_in[2] (edge_type_mask) unused: type is range-derivable for this dataset.
    const float* W1 = (const float*)d_in[6];     // [3, 32]
    const float* b1 = (const float*)d_in[7];     // [32]
    const float* W2 = (const float*)d_in[8];     // [32, 1]
    const float* b2 = (const float*)d_in[9];     // [1]

    int* loc_win  = (int*)d_ws;
    int* seq_win  = loc_win + (size_t)N_LOCS * N_LOCS;
    int* item_win = seq_win + (size_t)N_ITEMS * N_ITEMS;
    int* item_loc = item_win + N_ITEMS;
    float* comps  = (float*)(item_loc + N_ITEMS);

    size_t win_bytes = ((size_t)N_LOCS * N_LOCS + (size_t)N_ITEMS * N_ITEMS + N_ITEMS)
                       * sizeof(int);
    // winners to -1
    hipMemsetAsync(loc_win, 0xFF, win_bytes, stream);
    // comps accumulators to 0 (must happen every call: harness doesn't re-poison)
    hipMemsetAsync(comps, 0, 3 * sizeof(float), stream);

    scatter_edges<<<4096, 256, 0, stream>>>(src, dst, loc_win, seq_win, item_win);
    resolve_items<<<(N_ITEMS + 255) / 256, 256, 0, stream>>>(dst, attr, item_win, loc_win,
                                                             item_loc, comps);
    seq_reduce<<<2048, 256, 0, stream>>>(attr, seq_win, loc_win, item_loc, comps);
    mlp_final<<<1, 64, 0, stream>>>(comps, W1, b1, W2, b2, (float*)d_out);
}

// Round 2
// 290.373 us; speedup vs baseline: 1.5964x; 1.5964x over previous
//
#include <hip/hip_runtime.h>

#define N_ITEMS   2000
#define N_STORAGE 4094
#define N_LOCS    4096        // N_STORAGE + 2
#define E_EDGES   4194304

// d_ws layout (int32 elements):
//   loc_win : N_LOCS*N_LOCS      winner edge-id for loc_mat[ls][ld], -1 = empty
//   seq_win : N_ITEMS*N_ITEMS    winner edge-id for seq_mat[i][j],  -1 = empty
//   item_win: N_ITEMS            winner edge-id for item_to_loc[i], -1 = empty
//   item_loc: N_ITEMS            resolved storage loc per item (0 if none)
//   comps   : 3 floats           [item_item_dist, start_dist, end_dist]

// Kernel A: item->loc winners. 1.4M atomics into 2000 slots (125 cache lines)
// serialized the old fused kernel; resolve per-block in LDS, flush distinct only.
__global__ void item_scatter(const int* __restrict__ src, const int* __restrict__ dst,
                             int* __restrict__ item_win) {
    __shared__ int lwin[N_ITEMS];
    for (int t = threadIdx.x; t < N_ITEMS; t += blockDim.x) lwin[t] = -1;
    __syncthreads();

    // 128 blocks x 256 thr; each thread 32 chunks of 4 consecutive edges (int4 loads)
    int tid = blockIdx.x * blockDim.x + threadIdx.x;
    #pragma unroll 4
    for (int c = 0; c < 32; ++c) {
        int base = (c * 32768 + tid) * 4;
        int4 s4 = *(const int4*)&src[base];
        int4 d4 = *(const int4*)&dst[base];
        int ss[4] = {s4.x, s4.y, s4.z, s4.w};
        int dd[4] = {d4.x, d4.y, d4.z, d4.w};
        #pragma unroll
        for (int k = 0; k < 4; ++k) {
            int s = ss[k];
            if (s < N_ITEMS) {
                unsigned li = (unsigned)(dd[k] - N_ITEMS);
                if (li < N_STORAGE) atomicMax(&lwin[s], base + k);
            }
        }
    }
    __syncthreads();
    for (int t = threadIdx.x; t < N_ITEMS; t += blockDim.x) {
        int w = lwin[t];
        if (w >= 0) atomicMax(&item_win[t], w);   // ~distinct-items per block only
    }
}

// Kernel B: seq (item-item) and loc (loc-loc) scatter — low-contention addresses.
// Exactly 4 edges per thread: one int4 load pair, then fire-and-forget atomics
// (no interleaved load-waits forcing atomic retirement via ordered vmcnt).
__global__ void scatter_seq_loc(const int* __restrict__ src, const int* __restrict__ dst,
                                int* __restrict__ loc_win, int* __restrict__ seq_win) {
    int tid = blockIdx.x * blockDim.x + threadIdx.x;
    int base = tid * 4;
    int4 s4 = *(const int4*)&src[base];
    int4 d4 = *(const int4*)&dst[base];
    int ss[4] = {s4.x, s4.y, s4.z, s4.w};
    int dd[4] = {d4.x, d4.y, d4.z, d4.w};
    #pragma unroll
    for (int k = 0; k < 4; ++k) {
        int s = ss[k], d = dd[k];
        if (s >= N_ITEMS) {
            unsigned ls = (unsigned)(s - N_ITEMS), ld = (unsigned)(d - N_ITEMS);
            if (ls < N_LOCS && ld < N_LOCS)
                atomicMax(&loc_win[ls * N_LOCS + ld], base + k);
        } else if ((unsigned)d < N_ITEMS) {
            atomicMax(&seq_win[s * N_ITEMS + d], base + k);
        }
        // type-2 handled by item_scatter
    }
}

// Resolve item_to_loc (last valid edge wins; default 0), and accumulate
// start_dist = sum_i loc_mat[N_STORAGE, loc_i], end_dist = sum_i loc_mat[loc_i, N_STORAGE+1]
__global__ void resolve_items(const int* __restrict__ dst, const float* __restrict__ attr,
                              const int* __restrict__ item_win, const int* __restrict__ loc_win,
                              int* __restrict__ item_loc, float* __restrict__ comps) {
    int i = blockIdx.x * blockDim.x + threadIdx.x;
    float sd = 0.f, ed = 0.f;
    if (i < N_ITEMS) {
        int w = item_win[i];
        int loc = (w >= 0) ? (dst[w] - N_ITEMS) : 0;
        item_loc[i] = loc;
        int lw1 = loc_win[N_STORAGE * N_LOCS + loc];          // start row
        int lw2 = loc_win[loc * N_LOCS + (N_STORAGE + 1)];    // end col
        sd = (lw1 >= 0) ? attr[lw1 * 2 + 0] : 0.f;
        ed = (lw2 >= 0) ? attr[lw2 * 2 + 0] : 0.f;
    }
    #pragma unroll
    for (int o = 32; o > 0; o >>= 1) {
        sd += __shfl_down(sd, o);
        ed += __shfl_down(ed, o);
    }
    if ((threadIdx.x & 63) == 0) {
        atomicAdd(&comps[1], sd);
        atomicAdd(&comps[2], ed);
    }
}

// item_item_dist = sum over seq slots with a winner and seq>0 of seq * loc_mat[loc_i, loc_j]
__global__ void seq_reduce(const float* __restrict__ attr, const int* __restrict__ seq_win,
                           const int* __restrict__ loc_win, const int* __restrict__ item_loc,
                           float* __restrict__ comps) {
    __shared__ int s_loc[N_ITEMS];
    for (int t = threadIdx.x; t < N_ITEMS; t += blockDim.x) s_loc[t] = item_loc[t];
    __syncthreads();

    const int total = N_ITEMS * N_ITEMS;
    int stride = gridDim.x * blockDim.x;
    float acc = 0.f;
    for (int slot = blockIdx.x * blockDim.x + threadIdx.x; slot < total; slot += stride) {
        int w = seq_win[slot];
        if (w < 0) continue;
        float seq = attr[w * 2 + 1];
        if (!(seq > 0.f)) continue;
        int i = slot / N_ITEMS;
        int j = slot - i * N_ITEMS;
        int lw = loc_win[s_loc[i] * N_LOCS + s_loc[j]];
        if (lw >= 0) acc += seq * attr[lw * 2 + 0];
    }
    #pragma unroll
    for (int o = 32; o > 0; o >>= 1) acc += __shfl_down(acc, o);
    if ((threadIdx.x & 63) == 0) atomicAdd(&comps[0], acc);
}

// pred = relu(comps @ W1 + b1) @ W2 + b2   (comps: [1,3], W1: [3,32], W2: [32,1])
__global__ void mlp_final(const float* __restrict__ comps, const float* __restrict__ W1,
                          const float* __restrict__ b1, const float* __restrict__ W2,
                          const float* __restrict__ b2, float* __restrict__ out) {
    int t = threadIdx.x;
    float v = 0.f;
    if (t < 32) {
        float h = comps[0] * W1[0 * 32 + t] + comps[1] * W1[1 * 32 + t] +
                  comps[2] * W1[2 * 32 + t] + b1[t];
        h = fmaxf(h, 0.f);
        v = h * W2[t];
    }
    #pragma unroll
    for (int o = 32; o > 0; o >>= 1) v += __shfl_down(v, o);
    if (t == 0) out[0] = v + b2[0];
}

extern "C" void kernel_launch(void* const* d_in, const int* in_sizes, int n_in,
                              void* d_out, int out_size, void* d_ws, size_t ws_size,
                              hipStream_t stream) {
    const int*   eidx = (const int*)d_in[0];     // [2, E] int32
    const int*   src  = eidx;
    const int*   dst  = eidx + E_EDGES;
    const float* attr = (const float*)d_in[1];   // [E, 2] f32
    // d_in[2] (edge_type_mask) unused: type is range-derivable for this dataset.
    const float* W1 = (const float*)d_in[6];     // [3, 32]
    const float* b1 = (const float*)d_in[7];     // [32]
    const float* W2 = (const float*)d_in[8];     // [32, 1]
    const float* b2 = (const float*)d_in[9];     // [1]

    int* loc_win  = (int*)d_ws;
    int* seq_win  = loc_win + (size_t)N_LOCS * N_LOCS;
    int* item_win = seq_win + (size_t)N_ITEMS * N_ITEMS;
    int* item_loc = item_win + N_ITEMS;
    float* comps  = (float*)(item_loc + N_ITEMS);

    size_t win_bytes = ((size_t)N_LOCS * N_LOCS + (size_t)N_ITEMS * N_ITEMS + N_ITEMS)
                       * sizeof(int);
    hipMemsetAsync(loc_win, 0xFF, win_bytes, stream);   // winners to -1
    hipMemsetAsync(comps, 0, 3 * sizeof(float), stream); // accumulators (re-zero every call)

    item_scatter<<<128, 256, 0, stream>>>(src, dst, item_win);
    scatter_seq_loc<<<4096, 256, 0, stream>>>(src, dst, loc_win, seq_win);
    resolve_items<<<(N_ITEMS + 255) / 256, 256, 0, stream>>>(dst, attr, item_win, loc_win,
                                                             item_loc, comps);
    seq_reduce<<<2048, 256, 0, stream>>>(attr, seq_win, loc_win, item_loc, comps);
    mlp_final<<<1, 64, 0, stream>>>(comps, W1, b1, W2, b2, (float*)d_out);
}

// Round 3
// 163.269 us; speedup vs baseline: 2.8392x; 1.7785x over previous
//
#include <hip/hip_runtime.h>

#define N_ITEMS   2000
#define N_STORAGE 4094
#define N_LOCS    4096        // N_STORAGE + 2
#define E_EDGES   4194304
#define RSUB      2048        // compacted loc sub-matrix dim (<= 2001 used)
#define ISC_BLKS  256         // item_scatter blocks

typedef unsigned long long u64;

__device__ __forceinline__ float lowf(u64 k) {
    return __uint_as_float((unsigned)(k & 0xFFFFFFFFull));
}

// ---- Kernel 1: item->loc winners, per-block LDS, no global atomics (slab + reduce)
__global__ void item_scatter(const int* __restrict__ src, const int* __restrict__ dst,
                             int* __restrict__ slab) {
    __shared__ int lwin[N_ITEMS];
    for (int t = threadIdx.x; t < N_ITEMS; t += 256) lwin[t] = -1;
    __syncthreads();
    int tid = blockIdx.x * 256 + threadIdx.x;     // 256 blocks x 256 thr
    #pragma unroll 4
    for (int c = 0; c < 16; ++c) {
        int base = (c * 65536 + tid) * 4;
        int4 s4 = *(const int4*)&src[base];
        int4 d4 = *(const int4*)&dst[base];
        int ss[4] = {s4.x, s4.y, s4.z, s4.w};
        int dd[4] = {d4.x, d4.y, d4.z, d4.w};
        #pragma unroll
        for (int k = 0; k < 4; ++k) {
            if (ss[k] < N_ITEMS) {
                unsigned li = (unsigned)(dd[k] - N_ITEMS);
                if (li < N_STORAGE) atomicMax(&lwin[ss[k]], base + k);
            }
        }
    }
    __syncthreads();
    for (int t = threadIdx.x; t < N_ITEMS; t += 256)
        slab[blockIdx.x * 2048 + t] = lwin[t];
}

// ---- Kernel 2: reduce slab -> item_loc; mark used rows/cols
__global__ void item_reduce(const int* __restrict__ slab, const int* __restrict__ dst,
                            int* __restrict__ item_loc, int* __restrict__ used_row,
                            int* __restrict__ used_col) {
    int i = blockIdx.x * 256 + threadIdx.x;
    if (i < N_ITEMS) {
        int w = -1;
        for (int b = 0; b < ISC_BLKS; ++b) w = max(w, slab[b * 2048 + i]);
        int loc = (w >= 0) ? (dst[w] - N_ITEMS) : 0;
        item_loc[i] = loc;
        used_row[loc] = 1;
        used_col[loc] = 1;
    }
    if (blockIdx.x == 0 && threadIdx.x == 0) {
        used_row[N_STORAGE] = 1;          // start depot row
        used_col[N_STORAGE + 1] = 1;      // end depot col
    }
}

// ---- Kernel 3: compact remap (order nondeterministic; result permutation-invariant)
__global__ void build_remap(const int* __restrict__ used_row, const int* __restrict__ used_col,
                            int* __restrict__ rrow, int* __restrict__ rcol,
                            int* __restrict__ cnts) {
    int l = blockIdx.x * 256 + threadIdx.x;
    if (l < N_LOCS) {
        if (used_row[l]) rrow[l] = atomicAdd(&cnts[0], 1);
        if (used_col[l]) rcol[l] = atomicAdd(&cnts[1], 1);
    }
}

// ---- Kernel 4: per-item remapped coords + depot remapped coords
__global__ void item_remap(const int* __restrict__ item_loc, const int* __restrict__ rrow,
                           const int* __restrict__ rcol, int* __restrict__ item_rr,
                           int* __restrict__ item_rc, int* __restrict__ rse) {
    int i = blockIdx.x * 256 + threadIdx.x;
    if (i < N_ITEMS) {
        int loc = item_loc[i];
        item_rr[i] = rrow[loc];
        item_rc[i] = rcol[loc];
    }
    if (blockIdx.x == 0 && threadIdx.x == 0) {
        rse[0] = rrow[N_STORAGE];
        rse[1] = rcol[N_STORAGE + 1];
    }
}

// ---- Kernel 5: seq + loc scatter, values packed with edge-id keys (last-wins by id)
__global__ void scatter_unified(const int* __restrict__ src, const int* __restrict__ dst,
                                const float* __restrict__ attr, const int* __restrict__ rrow,
                                const int* __restrict__ rcol, u64* __restrict__ seq64,
                                u64* __restrict__ loc64) {
    int tid = blockIdx.x * 256 + threadIdx.x;     // 4096 blocks
    int base = tid * 4;
    int4 s4 = *(const int4*)&src[base];
    int4 d4 = *(const int4*)&dst[base];
    float4 a0 = *(const float4*)&attr[base * 2];       // edges base, base+1
    float4 a1 = *(const float4*)&attr[base * 2 + 4];   // edges base+2, base+3
    int ss[4] = {s4.x, s4.y, s4.z, s4.w};
    int dd[4] = {d4.x, d4.y, d4.z, d4.w};
    float av0[4] = {a0.x, a0.z, a1.x, a1.z};  // attr[:,0]
    float av1[4] = {a0.y, a0.w, a1.y, a1.w};  // attr[:,1]
    #pragma unroll
    for (int k = 0; k < 4; ++k) {
        int s = ss[k], d = dd[k];
        if (s >= N_ITEMS) {
            unsigned ls = (unsigned)(s - N_ITEMS), ld = (unsigned)(d - N_ITEMS);
            if (ls < N_LOCS && ld < N_LOCS) {
                int rr = rrow[ls], rc = rcol[ld];
                if (rr >= 0 && rc >= 0) {
                    u64 key = ((u64)(unsigned)(base + k) << 32) | (u64)__float_as_uint(av0[k]);
                    atomicMax(&loc64[(size_t)rr * RSUB + rc], key);
                }
            }
        } else if ((unsigned)d < N_ITEMS) {
            u64 key = ((u64)(unsigned)(base + k) << 32) | (u64)__float_as_uint(av1[k]);
            atomicMax(&seq64[(size_t)s * N_ITEMS + d], key);
        }
    }
}

// ---- Kernel 6: one block per item row; loc row staged coalesced in LDS; no random HBM
__global__ void seq_rows(const u64* __restrict__ seq64, const u64* __restrict__ loc64,
                         const int* __restrict__ item_rr, const int* __restrict__ item_rc,
                         float* __restrict__ comps) {
    __shared__ float locval[RSUB];   // 8 KB
    __shared__ int   rc_s[N_ITEMS];  // 8 KB
    __shared__ float wsum[4];
    int i = blockIdx.x;
    int rr = item_rr[i];
    const u64* lrow = loc64 + (size_t)rr * RSUB;
    for (int c = threadIdx.x; c < RSUB; c += 256) locval[c] = lowf(lrow[c]);
    for (int t = threadIdx.x; t < N_ITEMS; t += 256) rc_s[t] = item_rc[t];
    __syncthreads();

    float acc = 0.f;
    const u64* srow = seq64 + (size_t)i * N_ITEMS;
    for (int j = threadIdx.x; j < N_ITEMS; j += 256) {
        float seq = lowf(srow[j]);               // empty slot -> 0.0 -> excluded
        if (seq > 0.f) acc += seq * locval[rc_s[j]];
    }
    #pragma unroll
    for (int o = 32; o > 0; o >>= 1) acc += __shfl_down(acc, o);
    if ((threadIdx.x & 63) == 0) wsum[threadIdx.x >> 6] = acc;
    __syncthreads();
    if (threadIdx.x == 0)
        atomicAdd(&comps[0], wsum[0] + wsum[1] + wsum[2] + wsum[3]);
}

// ---- Kernel 7: depot sums + MLP, single block
__global__ void depot_mlp(const u64* __restrict__ loc64, const int* __restrict__ item_rr,
                          const int* __restrict__ item_rc, const int* __restrict__ rse,
                          const float* __restrict__ comps, const float* __restrict__ W1,
                          const float* __restrict__ b1, const float* __restrict__ W2,
                          const float* __restrict__ b2, float* __restrict__ out) {
    __shared__ float ssd[4], sed[4];
    int t = threadIdx.x;
    int rs = rse[0], re = rse[1];
    float sd = 0.f, ed = 0.f;
    for (int i = t; i < N_ITEMS; i += 256) {
        sd += lowf(loc64[(size_t)rs * RSUB + item_rc[i]]);
        ed += lowf(loc64[(size_t)item_rr[i] * RSUB + re]);
    }
    #pragma unroll
    for (int o = 32; o > 0; o >>= 1) {
        sd += __shfl_down(sd, o);
        ed += __shfl_down(ed, o);
    }
    if ((t & 63) == 0) { ssd[t >> 6] = sd; sed[t >> 6] = ed; }
    __syncthreads();
    float c1 = ssd[0] + ssd[1] + ssd[2] + ssd[3];
    float c2 = sed[0] + sed[1] + sed[2] + sed[3];
    float v = 0.f;
    if (t < 32) {
        float c0 = comps[0];
        float h = c0 * W1[t] + c1 * W1[32 + t] + c2 * W1[64 + t] + b1[t];
        h = fmaxf(h, 0.f);
        v = h * W2[t];
    }
    #pragma unroll
    for (int o = 32; o > 0; o >>= 1) v += __shfl_down(v, o);
    if (t == 0) out[0] = v + b2[0];
}

extern "C" void kernel_launch(void* const* d_in, const int* in_sizes, int n_in,
                              void* d_out, int out_size, void* d_ws, size_t ws_size,
                              hipStream_t stream) {
    const int*   eidx = (const int*)d_in[0];     // [2, E] int32
    const int*   src  = eidx;
    const int*   dst  = eidx + E_EDGES;
    const float* attr = (const float*)d_in[1];   // [E, 2] f32
    // d_in[2] (edge_type_mask) unused: type is range-derivable for this dataset.
    const float* W1 = (const float*)d_in[6];
    const float* b1 = (const float*)d_in[7];
    const float* W2 = (const float*)d_in[8];
    const float* b2 = (const float*)d_in[9];

    // ws layout (64-bit arrays first for alignment)
    u64* seq64 = (u64*)d_ws;                           // 4,000,000
    u64* loc64 = seq64 + (size_t)N_ITEMS * N_ITEMS;    // RSUB*RSUB = 4,194,304
    int* slab     = (int*)(loc64 + (size_t)RSUB * RSUB); // ISC_BLKS*2048
    int* rrow     = slab + ISC_BLKS * 2048;            // 4096  (init 0xFF)
    int* rcol     = rrow + N_LOCS;                     // 4096  (init 0xFF)
    int* used_row = rcol + N_LOCS;                     // 4096  (init 0)
    int* used_col = used_row + N_LOCS;                 // 4096  (init 0)
    int* cnts     = used_col + N_LOCS;                 // 2     (init 0)
    float* comps  = (float*)(cnts + 2);                // 3     (init 0)
    int* item_loc = (int*)(comps + 3);                 // 2000  (fully overwritten)
    int* item_rr  = item_loc + N_ITEMS;                // 2000
    int* item_rc  = item_rr + N_ITEMS;                 // 2000
    int* rse      = item_rc + N_ITEMS;                 // 2

    // zero the packed winner matrices (empty key 0 -> value 0.0 -> contributes 0)
    hipMemsetAsync(seq64, 0,
                   ((size_t)N_ITEMS * N_ITEMS + (size_t)RSUB * RSUB) * sizeof(u64), stream);
    hipMemsetAsync(rrow, 0xFF, 2 * N_LOCS * sizeof(int), stream);
    hipMemsetAsync(used_row, 0, (2 * N_LOCS + 2) * sizeof(int) + 3 * sizeof(float), stream);

    item_scatter <<<ISC_BLKS, 256, 0, stream>>>(src, dst, slab);
    item_reduce  <<<8, 256, 0, stream>>>(slab, dst, item_loc, used_row, used_col);
    build_remap  <<<16, 256, 0, stream>>>(used_row, used_col, rrow, rcol, cnts);
    item_remap   <<<8, 256, 0, stream>>>(item_loc, rrow, rcol, item_rr, item_rc, rse);
    scatter_unified<<<4096, 256, 0, stream>>>(src, dst, attr, rrow, rcol, seq64, loc64);
    seq_rows     <<<N_ITEMS, 256, 0, stream>>>(seq64, loc64, item_rr, item_rc, comps);
    depot_mlp    <<<1, 256, 0, stream>>>(loc64, item_rr, item_rc, rse, comps,
                                         W1, b1, W2, b2, (float*)d_out);
}

// Round 5
// 162.276 us; speedup vs baseline: 2.8566x; 1.0061x over previous
//
#include <hip/hip_runtime.h>

#define N_ITEMS   2000
#define N_STORAGE 4094
#define N_LOCS    4096        // N_STORAGE + 2
#define E_EDGES   4194304
#define RSUB      2048        // compacted loc sub-matrix dim (<= 2001 used)
#define ISC_BLKS  256

typedef unsigned long long u64;
typedef int   vi4 __attribute__((ext_vector_type(4)));
typedef float vf4 __attribute__((ext_vector_type(4)));

__device__ __forceinline__ float lowf(u64 k) {
    return __uint_as_float((unsigned)(k & 0xFFFFFFFFull));
}

// ---- Kernel 1: item->loc winners, per-block LDS, slab + reduce (no global atomics)
__global__ void item_scatter(const int* __restrict__ src, const int* __restrict__ dst,
                             int* __restrict__ slab) {
    __shared__ int lwin[N_ITEMS];
    for (int t = threadIdx.x; t < N_ITEMS; t += 256) lwin[t] = -1;
    __syncthreads();
    int tid = blockIdx.x * 256 + threadIdx.x;     // 256 blocks x 256 thr
    #pragma unroll 4
    for (int c = 0; c < 16; ++c) {
        int base = (c * 65536 + tid) * 4;
        vi4 s4 = __builtin_nontemporal_load((const vi4*)&src[base]);
        vi4 d4 = __builtin_nontemporal_load((const vi4*)&dst[base]);
        #pragma unroll
        for (int k = 0; k < 4; ++k) {
            if (s4[k] < N_ITEMS) {
                unsigned li = (unsigned)(d4[k] - N_ITEMS);
                if (li < N_STORAGE) atomicMax(&lwin[s4[k]], base + k);
            }
        }
    }
    __syncthreads();
    for (int t = threadIdx.x; t < N_ITEMS; t += 256)
        slab[blockIdx.x * 2048 + t] = lwin[t];
}

// ---- Kernel 2: slab -> item_loc; mark used rows/cols (+depot)
__global__ void item_reduce(const int* __restrict__ slab, const int* __restrict__ dst,
                            int* __restrict__ item_loc, int* __restrict__ used_row,
                            int* __restrict__ used_col) {
    int i = blockIdx.x * 256 + threadIdx.x;
    if (i < N_ITEMS) {
        int w = -1;
        for (int b = 0; b < ISC_BLKS; ++b) w = max(w, slab[b * 2048 + i]);
        int loc = (w >= 0) ? (dst[w] - N_ITEMS) : 0;
        item_loc[i] = loc;
        used_row[loc] = 1;
        used_col[loc] = 1;
    }
    if (blockIdx.x == 0 && threadIdx.x == 0) {
        used_row[N_STORAGE] = 1;          // start depot row
        used_col[N_STORAGE + 1] = 1;      // end depot col
    }
}

// ---- Kernel 3 (fused): compact remap + per-item remapped coords + depot coords.
// Single block; labels order-nondeterministic but result is permutation-invariant.
__global__ void remap_fused(const int* __restrict__ used_row, const int* __restrict__ used_col,
                            const int* __restrict__ item_loc, int* __restrict__ rrow,
                            int* __restrict__ rcol, int* __restrict__ item_rr,
                            int* __restrict__ item_rc, int* __restrict__ rse) {
    __shared__ int c[2];
    if (threadIdx.x < 2) c[threadIdx.x] = 0;
    __syncthreads();
    for (int l = threadIdx.x; l < N_LOCS; l += 256) {
        if (used_row[l]) rrow[l] = atomicAdd(&c[0], 1);
        if (used_col[l]) rcol[l] = atomicAdd(&c[1], 1);
    }
    __syncthreads();   // block-scope fence: rrow/rcol visible within block
    for (int i = threadIdx.x; i < N_ITEMS; i += 256) {
        int loc = item_loc[i];
        item_rr[i] = rrow[loc];
        item_rc[i] = rcol[loc];
    }
    if (threadIdx.x == 0) {
        rse[0] = rrow[N_STORAGE];
        rse[1] = rcol[N_STORAGE + 1];
    }
}

// ---- Kernel 4: scatter. seq: 32-bit edge-id winners. loc: u64 (id<<32|val) winners.
__global__ void scatter_unified(const int* __restrict__ src, const int* __restrict__ dst,
                                const float* __restrict__ attr, const int* __restrict__ rrow,
                                const int* __restrict__ rcol, int* __restrict__ seq32,
                                u64* __restrict__ loc64) {
    int tid = blockIdx.x * 256 + threadIdx.x;     // 4096 blocks
    int base = tid * 4;
    vi4 s4 = __builtin_nontemporal_load((const vi4*)&src[base]);
    vi4 d4 = __builtin_nontemporal_load((const vi4*)&dst[base]);
    vf4 a0 = __builtin_nontemporal_load((const vf4*)&attr[base * 2]);
    vf4 a1 = __builtin_nontemporal_load((const vf4*)&attr[base * 2 + 4]);
    float av0[4] = {a0[0], a0[2], a1[0], a1[2]};  // attr[:,0] per edge
    #pragma unroll
    for (int k = 0; k < 4; ++k) {
        int s = s4[k], d = d4[k];
        if (s >= N_ITEMS) {
            unsigned ls = (unsigned)(s - N_ITEMS), ld = (unsigned)(d - N_ITEMS);
            if (ls < N_LOCS && ld < N_LOCS) {
                int rr = rrow[ls], rc = rcol[ld];
                if (rr >= 0 && rc >= 0) {
                    u64 key = ((u64)(unsigned)(base + k) << 32) | (u64)__float_as_uint(av0[k]);
                    atomicMax(&loc64[(size_t)rr * RSUB + rc], key);
                }
            }
        } else if ((unsigned)d < N_ITEMS) {
            atomicMax(&seq32[s * N_ITEMS + d], base + k);   // init -1; ids >= 0
        }
    }
}

// ---- Kernel 5: one block per item row; loc row staged in LDS; per-block partial (no atomics)
__global__ void seq_rows(const int* __restrict__ seq32, const u64* __restrict__ loc64,
                         const float* __restrict__ attr, const int* __restrict__ item_rr,
                         const int* __restrict__ item_rc, float* __restrict__ part) {
    __shared__ float locval[RSUB];   // 8 KB
    __shared__ int   rc_s[N_ITEMS];  // 8 KB
    __shared__ float wsum[4];
    int i = blockIdx.x;
    int rr = item_rr[i];
    const u64* lrow = loc64 + (size_t)rr * RSUB;
    for (int c = threadIdx.x; c < RSUB; c += 256) locval[c] = lowf(lrow[c]);
    for (int t = threadIdx.x; t < N_ITEMS; t += 256) rc_s[t] = item_rc[t];
    __syncthreads();

    float acc = 0.f;
    const int* srow = seq32 + (size_t)i * N_ITEMS;
    for (int j = threadIdx.x; j < N_ITEMS; j += 256) {
        int w = srow[j];                          // -1 = empty
        if (w >= 0) {
            float seq = attr[(w << 1) + 1];       // random gather, TLP-hidden
            if (seq > 0.f) acc += seq * locval[rc_s[j]];
        }
    }
    #pragma unroll
    for (int o = 32; o > 0; o >>= 1) acc += __shfl_down(acc, o);
    if ((threadIdx.x & 63) == 0) wsum[threadIdx.x >> 6] = acc;
    __syncthreads();
    if (threadIdx.x == 0)
        part[i] = wsum[0] + wsum[1] + wsum[2] + wsum[3];
}

// ---- Kernel 6: sum partials + depot sums + MLP, single block
__global__ void final_mlp(const float* __restrict__ part, const u64* __restrict__ loc64,
                          const int* __restrict__ item_rr, const int* __restrict__ item_rc,
                          const int* __restrict__ rse, const float* __restrict__ W1,
                          const float* __restrict__ b1, const float* __restrict__ W2,
                          const float* __restrict__ b2, float* __restrict__ out) {
    __shared__ float s0[4], s1[4], s2[4];
    int t = threadIdx.x;
    int rs = rse[0], re = rse[1];
    float c0 = 0.f, sd = 0.f, ed = 0.f;
    for (int i = t; i < N_ITEMS; i += 256) {
        c0 += part[i];
        sd += lowf(loc64[(size_t)rs * RSUB + item_rc[i]]);
        ed += lowf(loc64[(size_t)item_rr[i] * RSUB + re]);
    }
    #pragma unroll
    for (int o = 32; o > 0; o >>= 1) {
        c0 += __shfl_down(c0, o);
        sd += __shfl_down(sd, o);
        ed += __shfl_down(ed, o);
    }
    if ((t & 63) == 0) { s0[t >> 6] = c0; s1[t >> 6] = sd; s2[t >> 6] = ed; }
    __syncthreads();
    float v = 0.f;
    if (t < 32) {
        float a = s0[0] + s0[1] + s0[2] + s0[3];
        float b = s1[0] + s1[1] + s1[2] + s1[3];
        float c = s2[0] + s2[1] + s2[2] + s2[3];
        float h = a * W1[t] + b * W1[32 + t] + c * W1[64 + t] + b1[t];
        h = fmaxf(h, 0.f);
        v = h * W2[t];
    }
    #pragma unroll
    for (int o = 32; o > 0; o >>= 1) v += __shfl_down(v, o);
    if (t == 0) out[0] = v + b2[0];
}

extern "C" void kernel_launch(void* const* d_in, const int* in_sizes, int n_in,
                              void* d_out, int out_size, void* d_ws, size_t ws_size,
                              hipStream_t stream) {
    const int*   eidx = (const int*)d_in[0];     // [2, E] int32
    const int*   src  = eidx;
    const int*   dst  = eidx + E_EDGES;
    const float* attr = (const float*)d_in[1];   // [E, 2] f32
    // d_in[2] (edge_type_mask) unused: type is range-derivable for this dataset.
    const float* W1 = (const float*)d_in[6];
    const float* b1 = (const float*)d_in[7];
    const float* W2 = (const float*)d_in[8];
    const float* b2 = (const float*)d_in[9];

    // ws layout: [zero-block: loc64, used_row, used_col][0xFF-block: seq32, rrow, rcol][rest]
    u64* loc64    = (u64*)d_ws;                          // RSUB*RSUB
    int* used_row = (int*)(loc64 + (size_t)RSUB * RSUB); // 4096
    int* used_col = used_row + N_LOCS;                   // 4096
    int* seq32    = used_col + N_LOCS;                   // N_ITEMS*N_ITEMS
    int* rrow     = seq32 + (size_t)N_ITEMS * N_ITEMS;   // 4096
    int* rcol     = rrow + N_LOCS;                       // 4096
    int* slab     = rcol + N_LOCS;                       // ISC_BLKS*2048
    int* item_loc = slab + ISC_BLKS * 2048;              // 2000
    int* item_rr  = item_loc + N_ITEMS;                  // 2000
    int* item_rc  = item_rr + N_ITEMS;                   // 2000
    int* rse      = item_rc + N_ITEMS;                   // 2
    float* part   = (float*)(rse + 2);                   // 2000 (fully overwritten)

    size_t z_bytes = (size_t)RSUB * RSUB * sizeof(u64) + 2 * N_LOCS * sizeof(int);
    size_t f_bytes = (size_t)N_ITEMS * N_ITEMS * sizeof(int) + 2 * N_LOCS * sizeof(int);
    hipMemsetAsync(loc64, 0, z_bytes, stream);      // loc64=0, used_row/col=0
    hipMemsetAsync(seq32, 0xFF, f_bytes, stream);   // seq32=-1, rrow/rcol=-1

    item_scatter   <<<ISC_BLKS, 256, 0, stream>>>(src, dst, slab);
    item_reduce    <<<8, 256, 0, stream>>>(slab, dst, item_loc, used_row, used_col);
    remap_fused    <<<1, 256, 0, stream>>>(used_row, used_col, item_loc, rrow, rcol,
                                           item_rr, item_rc, rse);
    scatter_unified<<<4096, 256, 0, stream>>>(src, dst, attr, rrow, rcol, seq32, loc64);
    seq_rows       <<<N_ITEMS, 256, 0, stream>>>(seq32, loc64, attr, item_rr, item_rc, part);
    final_mlp      <<<1, 256, 0, stream>>>(part, loc64, item_rr, item_rc, rse,
                                           W1, b1, W2, b2, (float*)d_out);
}

// Round 6
// 155.236 us; speedup vs baseline: 2.9862x; 1.0454x over previous
//
#include <hip/hip_runtime.h>

#define N_ITEMS   2000
#define N_STORAGE 4094
#define N_LOCS    4096        // N_STORAGE + 2
#define E_EDGES   4194304
#define RSUB      2048        // compacted loc sub-matrix dim (<= 2001 used)
#define ISC_BLKS  256

typedef unsigned long long u64;
typedef int   vi4 __attribute__((ext_vector_type(4)));
typedef float vf4 __attribute__((ext_vector_type(4)));

__device__ __forceinline__ float lowf(u64 k) {
    return __uint_as_float((unsigned)(k & 0xFFFFFFFFull));
}

// ---- Kernel 1 (fused): item->loc winners in LDS (slab out) + global seq scatter.
// seq32 stores edge_id+1 (0 = empty) so the workspace needs only one zero-memset.
__global__ void item_seq_scatter(const int* __restrict__ src, const int* __restrict__ dst,
                                 int* __restrict__ slab, int* __restrict__ seq32) {
    __shared__ int lwin[N_ITEMS];
    for (int t = threadIdx.x; t < N_ITEMS; t += 1024) lwin[t] = -1;
    __syncthreads();
    int tid = blockIdx.x * 1024 + threadIdx.x;    // 256 blocks x 1024 thr
    #pragma unroll
    for (int c = 0; c < 4; ++c) {
        int base = (c * 262144 + tid) * 4;
        vi4 s4 = __builtin_nontemporal_load((const vi4*)&src[base]);
        vi4 d4 = __builtin_nontemporal_load((const vi4*)&dst[base]);
        #pragma unroll
        for (int k = 0; k < 4; ++k) {
            int s = s4[k], d = d4[k];
            if ((unsigned)s < N_ITEMS) {
                if ((unsigned)d < N_ITEMS) {
                    atomicMax(&seq32[s * N_ITEMS + d], base + k + 1);  // type 1
                } else {
                    unsigned li = (unsigned)(d - N_ITEMS);
                    if (li < N_STORAGE) atomicMax(&lwin[s], base + k); // type 2
                }
            }
        }
    }
    __syncthreads();
    for (int t = threadIdx.x; t < N_ITEMS; t += 1024)
        slab[blockIdx.x * 2048 + t] = lwin[t];
}

// ---- Kernel 2: slab -> item_loc; mark used rows/cols (+depot)
__global__ void item_reduce(const int* __restrict__ slab, const int* __restrict__ dst,
                            int* __restrict__ item_loc, int* __restrict__ used_row,
                            int* __restrict__ used_col) {
    int i = blockIdx.x * 256 + threadIdx.x;
    if (i < N_ITEMS) {
        int w = -1;
        for (int b = 0; b < ISC_BLKS; ++b) w = max(w, slab[b * 2048 + i]);
        int loc = (w >= 0) ? (dst[w] - N_ITEMS) : 0;
        item_loc[i] = loc;
        used_row[loc] = 1;
        used_col[loc] = 1;
    }
    if (blockIdx.x == 0 && threadIdx.x == 0) {
        used_row[N_STORAGE] = 1;          // start depot row
        used_col[N_STORAGE + 1] = 1;      // end depot col
    }
}

// ---- Kernel 3 (fused): compact remap (label+1; 0 = unused) + per-item coords + depot.
// Single block; label order nondeterministic but result permutation-invariant.
__global__ void remap_fused(const int* __restrict__ used_row, const int* __restrict__ used_col,
                            const int* __restrict__ item_loc, int* __restrict__ rrow,
                            int* __restrict__ rcol, int* __restrict__ item_rr,
                            int* __restrict__ item_rc, int* __restrict__ rse) {
    __shared__ int c[2];
    if (threadIdx.x < 2) c[threadIdx.x] = 0;
    __syncthreads();
    for (int l = threadIdx.x; l < N_LOCS; l += 256) {
        if (used_row[l]) rrow[l] = atomicAdd(&c[0], 1) + 1;
        if (used_col[l]) rcol[l] = atomicAdd(&c[1], 1) + 1;
    }
    __syncthreads();   // block-scope fence: rrow/rcol visible within block
    for (int i = threadIdx.x; i < N_ITEMS; i += 256) {
        int loc = item_loc[i];
        item_rr[i] = rrow[loc] - 1;       // guaranteed used -> >0
        item_rc[i] = rcol[loc] - 1;
    }
    if (threadIdx.x == 0) {
        rse[0] = rrow[N_STORAGE] - 1;
        rse[1] = rcol[N_STORAGE + 1] - 1;
    }
}

// ---- Kernel 4: loc-loc scatter only (~24% of loc edges pass the used filter).
// loc64 key = (edge_id+1)<<32 | val_bits; 0 = empty.
__global__ void scatter_loc(const int* __restrict__ src, const int* __restrict__ dst,
                            const float* __restrict__ attr, const int* __restrict__ rrow,
                            const int* __restrict__ rcol, u64* __restrict__ loc64) {
    int tid = blockIdx.x * 256 + threadIdx.x;     // 4096 blocks
    int base = tid * 4;
    vi4 s4 = __builtin_nontemporal_load((const vi4*)&src[base]);
    vi4 d4 = __builtin_nontemporal_load((const vi4*)&dst[base]);
    vf4 a0 = __builtin_nontemporal_load((const vf4*)&attr[base * 2]);
    vf4 a1 = __builtin_nontemporal_load((const vf4*)&attr[base * 2 + 4]);
    float av0[4] = {a0[0], a0[2], a1[0], a1[2]};  // attr[:,0] per edge
    #pragma unroll
    for (int k = 0; k < 4; ++k) {
        int s = s4[k];
        if (s >= N_ITEMS) {
            unsigned ls = (unsigned)(s - N_ITEMS), ld = (unsigned)(d4[k] - N_ITEMS);
            if (ls < N_LOCS && ld < N_LOCS) {
                int rr = rrow[ls], rc = rcol[ld];
                if (rr > 0 && rc > 0) {
                    u64 key = ((u64)(unsigned)(base + k + 1) << 32)
                            | (u64)__float_as_uint(av0[k]);
                    atomicMax(&loc64[(size_t)(rr - 1) * RSUB + (rc - 1)], key);
                }
            }
        }
    }
}

// ---- Kernel 5: one block per item row; loc row staged in LDS; partials (no atomics).
// Also emits parte[i] = loc_mat[loc_i, end] (end-depot term) from the staged row.
__global__ void seq_rows(const int* __restrict__ seq32, const u64* __restrict__ loc64,
                         const float* __restrict__ attr, const int* __restrict__ item_rr,
                         const int* __restrict__ item_rc, const int* __restrict__ rse,
                         float* __restrict__ part, float* __restrict__ parte) {
    __shared__ float locval[RSUB];   // 8 KB
    __shared__ int   rc_s[N_ITEMS];  // 8 KB
    __shared__ float wsum[4];
    int i = blockIdx.x;
    int rr = item_rr[i];
    const u64* lrow = loc64 + (size_t)rr * RSUB;
    for (int c = threadIdx.x; c < RSUB; c += 256) locval[c] = lowf(lrow[c]);
    for (int t = threadIdx.x; t < N_ITEMS; t += 256) rc_s[t] = item_rc[t];
    __syncthreads();

    float acc = 0.f;
    const int* srow = seq32 + (size_t)i * N_ITEMS;
    for (int j = threadIdx.x; j < N_ITEMS; j += 256) {
        int w = srow[j];                          // 0 = empty, else edge_id+1
        if (w > 0) {
            float seq = attr[((w - 1) << 1) + 1]; // random gather, TLP-hidden
            if (seq > 0.f) acc += seq * locval[rc_s[j]];
        }
    }
    #pragma unroll
    for (int o = 32; o > 0; o >>= 1) acc += __shfl_down(acc, o);
    if ((threadIdx.x & 63) == 0) wsum[threadIdx.x >> 6] = acc;
    __syncthreads();
    if (threadIdx.x == 0) {
        part[i]  = wsum[0] + wsum[1] + wsum[2] + wsum[3];
        parte[i] = locval[rse[1]];                // end-depot term for this item
    }
}

// ---- Kernel 6: sum partials + start-depot gathers + MLP, single block
__global__ void final_mlp(const float* __restrict__ part, const float* __restrict__ parte,
                          const u64* __restrict__ loc64, const int* __restrict__ item_rc,
                          const int* __restrict__ rse, const float* __restrict__ W1,
                          const float* __restrict__ b1, const float* __restrict__ W2,
                          const float* __restrict__ b2, float* __restrict__ out) {
    __shared__ float s0[4], s1[4], s2[4];
    int t = threadIdx.x;
    int rs = rse[0];
    float c0 = 0.f, sd = 0.f, ed = 0.f;
    for (int i = t; i < N_ITEMS; i += 256) {
        c0 += part[i];
        ed += parte[i];
        sd += lowf(loc64[(size_t)rs * RSUB + item_rc[i]]);
    }
    #pragma unroll
    for (int o = 32; o > 0; o >>= 1) {
        c0 += __shfl_down(c0, o);
        sd += __shfl_down(sd, o);
        ed += __shfl_down(ed, o);
    }
    if ((t & 63) == 0) { s0[t >> 6] = c0; s1[t >> 6] = sd; s2[t >> 6] = ed; }
    __syncthreads();
    float v = 0.f;
    if (t < 32) {
        float a = s0[0] + s0[1] + s0[2] + s0[3];
        float b = s1[0] + s1[1] + s1[2] + s1[3];
        float c = s2[0] + s2[1] + s2[2] + s2[3];
        float h = a * W1[t] + b * W1[32 + t] + c * W1[64 + t] + b1[t];
        h = fmaxf(h, 0.f);
        v = h * W2[t];
    }
    #pragma unroll
    for (int o = 32; o > 0; o >>= 1) v += __shfl_down(v, o);
    if (t == 0) out[0] = v + b2[0];
}

extern "C" void kernel_launch(void* const* d_in, const int* in_sizes, int n_in,
                              void* d_out, int out_size, void* d_ws, size_t ws_size,
                              hipStream_t stream) {
    const int*   eidx = (const int*)d_in[0];     // [2, E] int32
    const int*   src  = eidx;
    const int*   dst  = eidx + E_EDGES;
    const float* attr = (const float*)d_in[1];   // [E, 2] f32
    // d_in[2] (edge_type_mask) unused: type is range-derivable for this dataset.
    const float* W1 = (const float*)d_in[6];
    const float* b1 = (const float*)d_in[7];
    const float* W2 = (const float*)d_in[8];
    const float* b2 = (const float*)d_in[9];

    // ws layout: one contiguous zero block [loc64|seq32|used_row|used_col|rrow|rcol],
    // then scratch that is fully overwritten every call.
    u64* loc64    = (u64*)d_ws;                          // RSUB*RSUB u64
    int* seq32    = (int*)(loc64 + (size_t)RSUB * RSUB); // N_ITEMS*N_ITEMS
    int* used_row = seq32 + (size_t)N_ITEMS * N_ITEMS;   // 4096
    int* used_col = used_row + N_LOCS;                   // 4096
    int* rrow     = used_col + N_LOCS;                   // 4096
    int* rcol     = rrow + N_LOCS;                       // 4096
    int* slab     = rcol + N_LOCS;                       // ISC_BLKS*2048
    int* item_loc = slab + ISC_BLKS * 2048;              // 2000
    int* item_rr  = item_loc + N_ITEMS;                  // 2000
    int* item_rc  = item_rr + N_ITEMS;                   // 2000
    int* rse      = item_rc + N_ITEMS;                   // 2
    float* part   = (float*)(rse + 2);                   // 2000 (fully overwritten)
    float* parte  = part + N_ITEMS;                      // 2000 (fully overwritten)

    size_t z_bytes = (size_t)RSUB * RSUB * sizeof(u64)
                   + (size_t)N_ITEMS * N_ITEMS * sizeof(int)
                   + 4 * N_LOCS * sizeof(int);
    hipMemsetAsync(loc64, 0, z_bytes, stream);  // loc64/seq32/used/rrow/rcol all zero

    item_seq_scatter<<<ISC_BLKS, 1024, 0, stream>>>(src, dst, slab, seq32);
    item_reduce     <<<8, 256, 0, stream>>>(slab, dst, item_loc, used_row, used_col);
    remap_fused     <<<1, 256, 0, stream>>>(used_row, used_col, item_loc, rrow, rcol,
                                            item_rr, item_rc, rse);
    scatter_loc     <<<4096, 256, 0, stream>>>(src, dst, attr, rrow, rcol, loc64);
    seq_rows        <<<N_ITEMS, 256, 0, stream>>>(seq32, loc64, attr, item_rr, item_rc,
                                                  rse, part, parte);
    final_mlp       <<<1, 256, 0, stream>>>(part, parte, loc64, item_rc, rse,
                                            W1, b1, W2, b2, (float*)d_out);
}